// Round 1
// baseline (1418.144 us; speedup 1.0000x reference)
//
#include <hip/hip_runtime.h>
#include <math.h>

// Problem constants (match reference setup_inputs()).
#define NNODES 10000
#define NEDGES 80000           // directed edges before self loops
#define ETOT   (NEDGES + NNODES)
#define F_IN   128

// ---------------------------------------------------------------------------
// CSR build (group edges by destination). Rebuilt every launch (ws poisoned).
// ---------------------------------------------------------------------------
__global__ void count_deg(const int* __restrict__ ei, int* __restrict__ indeg,
                          int E, int n) {
    int i = blockIdx.x * blockDim.x + threadIdx.x;
    if (i >= E + n) return;
    int dst = (i < E) ? ei[E + i] : (i - E);   // ei[E+i] = dst row; self loop otherwise
    atomicAdd(&indeg[dst], 1);
}

// Single-block exclusive scan over indeg -> row_ptr (and cursor copy).
__global__ void scan_rowptr(const int* __restrict__ indeg, int* __restrict__ row_ptr,
                            int* __restrict__ cursor, int n) {
    __shared__ int sums[1024];
    int tid = threadIdx.x;
    int per = (n + 1023) / 1024;
    int start = tid * per;
    int end = start + per; if (end > n) end = n;
    int s = 0;
    for (int i = start; i < end; ++i) s += indeg[i];
    sums[tid] = s;
    __syncthreads();
    // Hillis-Steele inclusive scan
    for (int off = 1; off < 1024; off <<= 1) {
        int v = (tid >= off) ? sums[tid - off] : 0;
        __syncthreads();
        sums[tid] += v;
        __syncthreads();
    }
    int excl = (tid == 0) ? 0 : sums[tid - 1];
    for (int i = start; i < end; ++i) {
        row_ptr[i] = excl;
        cursor[i]  = excl;
        excl += indeg[i];
    }
    if (tid == 1023) row_ptr[n] = sums[1023];
}

__global__ void scatter_edges(const int* __restrict__ ei, int* __restrict__ cursor,
                              int* __restrict__ col, int E, int n) {
    int i = blockIdx.x * blockDim.x + threadIdx.x;
    if (i >= E + n) return;
    int src, dst;
    if (i < E) { src = ei[i]; dst = ei[E + i]; }
    else       { src = i - E; dst = i - E; }
    int pos = atomicAdd(&cursor[dst], 1);   // cursor pre-initialized to row_ptr
    col[pos] = src;
}

// ---------------------------------------------------------------------------
// fp32 tiled GEMM: C[M,N] = A[M,K] @ B[K,N], row-major. K % 16 == 0 (all layers).
// 64x64 tile, 256 threads, 4x4 micro-tile per thread.
// ---------------------------------------------------------------------------
#define BM 64
#define BN 64
#define BK 16
__global__ __launch_bounds__(256) void gemm_nn(const float* __restrict__ A,
                                               const float* __restrict__ B,
                                               float* __restrict__ C,
                                               int M, int N, int K) {
    __shared__ float As[BK][BM + 1];
    __shared__ float Bs[BK][BN + 1];
    int tid = threadIdx.x;
    int bm = blockIdx.y * BM;
    int bn = blockIdx.x * BN;
    int tx = tid & 15;        // 0..15 -> 4 cols each
    int ty = tid >> 4;        // 0..15 -> 4 rows each
    float acc[4][4];
    #pragma unroll
    for (int i = 0; i < 4; ++i)
        #pragma unroll
        for (int j = 0; j < 4; ++j) acc[i][j] = 0.f;

    for (int k0 = 0; k0 < K; k0 += BK) {
        // load A tile (BM x BK), store transposed As[k][m]
        #pragma unroll
        for (int i = tid; i < BM * BK; i += 256) {
            int m = i / BK, k = i % BK;
            int gm = bm + m;
            As[k][m] = (gm < M) ? A[(size_t)gm * K + (k0 + k)] : 0.f;
        }
        // load B tile (BK x BN)
        #pragma unroll
        for (int i = tid; i < BK * BN; i += 256) {
            int k = i / BN, nn = i % BN;
            int gn = bn + nn;
            Bs[k][nn] = (gn < N) ? B[(size_t)(k0 + k) * N + gn] : 0.f;
        }
        __syncthreads();
        #pragma unroll
        for (int k = 0; k < BK; ++k) {
            float a[4], b[4];
            #pragma unroll
            for (int i = 0; i < 4; ++i) a[i] = As[k][ty * 4 + i];
            #pragma unroll
            for (int j = 0; j < 4; ++j) b[j] = Bs[k][tx * 4 + j];
            #pragma unroll
            for (int i = 0; i < 4; ++i)
                #pragma unroll
                for (int j = 0; j < 4; ++j) acc[i][j] += a[i] * b[j];
        }
        __syncthreads();
    }
    #pragma unroll
    for (int i = 0; i < 4; ++i) {
        int gm = bm + ty * 4 + i;
        if (gm >= M) continue;
        #pragma unroll
        for (int j = 0; j < 4; ++j) {
            int gn = bn + tx * 4 + j;
            if (gn < N) C[(size_t)gm * N + gn] = acc[i][j];
        }
    }
}

// ---------------------------------------------------------------------------
// e_src[n,H], e_dst[n,H]: per-(node,head) dot of h[n,h,:] with a_src/a_dst.
// One wave per (node, head).
// ---------------------------------------------------------------------------
__global__ __launch_bounds__(64) void attn_halves(const float* __restrict__ h,
                                                  const float* __restrict__ a_src,
                                                  const float* __restrict__ a_dst,
                                                  float* __restrict__ e_src,
                                                  float* __restrict__ e_dst,
                                                  int H, int C) {
    int wid = blockIdx.x;          // node*H + head
    int head = wid % H;
    int lane = threadIdx.x;
    const float* hp = h + (size_t)wid * C;
    const float* as = a_src + head * C;
    const float* ad = a_dst + head * C;
    float s1 = 0.f, s2 = 0.f;
    for (int c = lane; c < C; c += 64) {
        float v = hp[c];
        s1 += v * as[c];
        s2 += v * ad[c];
    }
    #pragma unroll
    for (int off = 32; off; off >>= 1) {
        s1 += __shfl_down(s1, off);
        s2 += __shfl_down(s2, off);
    }
    if (lane == 0) { e_src[wid] = s1; e_dst[wid] = s2; }
}

// ---------------------------------------------------------------------------
// Aggregation: one wave per (dst,head). Segment max -> denom -> weighted sum,
// fused bias + outer LeakyReLU(0.1). h layout [n,H,C]; out layout [n,H*C].
// ---------------------------------------------------------------------------
template <int NCHUNK>
__global__ __launch_bounds__(64) void aggregate(const float* __restrict__ h,
                                                const float* __restrict__ e_src,
                                                const float* __restrict__ e_dst,
                                                const int* __restrict__ row_ptr,
                                                const int* __restrict__ col,
                                                const float* __restrict__ bias,
                                                float* __restrict__ out,
                                                int H, int C) {
    int wid = blockIdx.x;
    int node = wid / H;
    int head = wid - node * H;
    int lane = threadIdx.x;
    int rs = row_ptr[node], re = row_ptr[node + 1];
    float edv = e_dst[(size_t)node * H + head];

    // pass 1: segment max of LeakyReLU(0.2) logits
    float mx = -INFINITY;
    for (int i = rs + lane; i < re; i += 64) {
        int s = col[i];
        float v = e_src[(size_t)s * H + head] + edv;
        v = (v > 0.f) ? v : 0.2f * v;
        mx = fmaxf(mx, v);
    }
    #pragma unroll
    for (int off = 32; off; off >>= 1) mx = fmaxf(mx, __shfl_down(mx, off));
    mx = __shfl(mx, 0);

    // pass 2: denom
    float dn = 0.f;
    for (int i = rs + lane; i < re; i += 64) {
        int s = col[i];
        float v = e_src[(size_t)s * H + head] + edv;
        v = (v > 0.f) ? v : 0.2f * v;
        dn += expf(v - mx);
    }
    #pragma unroll
    for (int off = 32; off; off >>= 1) dn += __shfl_down(dn, off);
    dn = __shfl(dn, 0);
    float rdn = 1.f / (dn + 1e-16f);

    // pass 3: weighted scatter-sum (sequential over edges, vector over channels)
    float acc[NCHUNK];
    #pragma unroll
    for (int k = 0; k < NCHUNK; ++k) acc[k] = 0.f;
    for (int i = rs; i < re; ++i) {
        int s = col[i];
        float v = e_src[(size_t)s * H + head] + edv;
        v = (v > 0.f) ? v : 0.2f * v;
        float w = expf(v - mx) * rdn;
        const float* hp = h + ((size_t)s * H + head) * C;
        #pragma unroll
        for (int k = 0; k < NCHUNK; ++k) {
            int c = k * 64 + lane;
            if (c < C) acc[k] += w * hp[c];
        }
    }

    // epilogue: + bias, outer LeakyReLU(0.1)
    float* op = out + ((size_t)node * H + head) * C;
    const float* bp = bias + head * C;
    #pragma unroll
    for (int k = 0; k < NCHUNK; ++k) {
        int c = k * 64 + lane;
        if (c < C) {
            float v = acc[k] + bp[c];
            v = (v > 0.f) ? v : 0.1f * v;
            op[c] = v;
        }
    }
}

// Final row softmax over 16 classes.
__global__ void softmax16(const float* __restrict__ in, float* __restrict__ out, int n) {
    int i = blockIdx.x * blockDim.x + threadIdx.x;
    if (i >= n) return;
    float v[16];
    float mx = -INFINITY;
    #pragma unroll
    for (int j = 0; j < 16; ++j) { v[j] = in[i * 16 + j]; mx = fmaxf(mx, v[j]); }
    float s = 0.f;
    #pragma unroll
    for (int j = 0; j < 16; ++j) { v[j] = expf(v[j] - mx); s += v[j]; }
    float r = 1.f / s;
    #pragma unroll
    for (int j = 0; j < 16; ++j) out[i * 16 + j] = v[j] * r;
}

// ---------------------------------------------------------------------------
extern "C" void kernel_launch(void* const* d_in, const int* in_sizes, int n_in,
                              void* d_out, int out_size, void* d_ws, size_t ws_size,
                              hipStream_t stream) {
    const float* x   = (const float*)d_in[0];
    const int*   ei  = (const int*)d_in[1];
    const float* W1  = (const float*)d_in[2];
    const float* as1 = (const float*)d_in[3];
    const float* ad1 = (const float*)d_in[4];
    const float* b1  = (const float*)d_in[5];
    const float* W2  = (const float*)d_in[6];
    const float* as2 = (const float*)d_in[7];
    const float* ad2 = (const float*)d_in[8];
    const float* b2  = (const float*)d_in[9];
    const float* W3  = (const float*)d_in[10];
    const float* as3 = (const float*)d_in[11];
    const float* ad3 = (const float*)d_in[12];
    const float* b3  = (const float*)d_in[13];
    const float* W4  = (const float*)d_in[14];
    const float* as4 = (const float*)d_in[15];
    const float* ad4 = (const float*)d_in[16];
    const float* b4  = (const float*)d_in[17];

    // workspace carve-out (256B aligned)
    char* ws = (char*)d_ws;
    size_t off = 0;
    auto alloc = [&](size_t bytes) -> void* {
        void* p = ws + off;
        off = (off + bytes + 255) & ~(size_t)255;
        return p;
    };
    const size_t BIG = (size_t)NNODES * 2560;          // max n x H*C
    float* bufA   = (float*)alloc(BIG * sizeof(float));       // projection h
    float* bufB   = (float*)alloc(BIG * sizeof(float));       // layer output / next input
    float* e_src  = (float*)alloc((size_t)NNODES * 10 * sizeof(float));
    float* e_dst  = (float*)alloc((size_t)NNODES * 10 * sizeof(float));
    int* indeg    = (int*)alloc(NNODES * sizeof(int));
    int* row_ptr  = (int*)alloc((NNODES + 1) * sizeof(int));
    int* cursor   = (int*)alloc(NNODES * sizeof(int));
    int* col      = (int*)alloc(ETOT * sizeof(int));
    (void)ws_size;

    // ---- CSR build ----
    hipMemsetAsync(indeg, 0, NNODES * sizeof(int), stream);
    int eb = (ETOT + 255) / 256;
    count_deg<<<eb, 256, 0, stream>>>(ei, indeg, NEDGES, NNODES);
    scan_rowptr<<<1, 1024, 0, stream>>>(indeg, row_ptr, cursor, NNODES);
    scatter_edges<<<eb, 256, 0, stream>>>(ei, cursor, col, NEDGES, NNODES);

    const int Mb = (NNODES + BM - 1) / BM;   // 157

    // ---- Layer 1: 128 -> 10 heads x 256, concat ----
    gemm_nn<<<dim3(2560 / BN, Mb), 256, 0, stream>>>(x, W1, bufA, NNODES, 2560, 128);
    attn_halves<<<NNODES * 10, 64, 0, stream>>>(bufA, as1, ad1, e_src, e_dst, 10, 256);
    aggregate<4><<<NNODES * 10, 64, 0, stream>>>(bufA, e_src, e_dst, row_ptr, col, b1,
                                                 bufB, 10, 256);

    // ---- Layer 2: 2560 -> 8 heads x 56, concat ----
    gemm_nn<<<dim3((448 + BN - 1) / BN, Mb), 256, 0, stream>>>(bufB, W2, bufA, NNODES, 448, 2560);
    attn_halves<<<NNODES * 8, 64, 0, stream>>>(bufA, as2, ad2, e_src, e_dst, 8, 56);
    aggregate<1><<<NNODES * 8, 64, 0, stream>>>(bufA, e_src, e_dst, row_ptr, col, b2,
                                                bufB, 8, 56);

    // ---- Layer 3: 448 -> 4 heads x 32, concat ----
    gemm_nn<<<dim3(128 / BN, Mb), 256, 0, stream>>>(bufB, W3, bufA, NNODES, 128, 448);
    attn_halves<<<NNODES * 4, 64, 0, stream>>>(bufA, as3, ad3, e_src, e_dst, 4, 32);
    aggregate<1><<<NNODES * 4, 64, 0, stream>>>(bufA, e_src, e_dst, row_ptr, col, b3,
                                                bufB, 4, 32);

    // ---- Layer 4: 128 -> 1 head x 16, mean(=identity) ----
    gemm_nn<<<dim3(1, Mb), 256, 0, stream>>>(bufB, W4, bufA, NNODES, 16, 128);
    attn_halves<<<NNODES * 1, 64, 0, stream>>>(bufA, as4, ad4, e_src, e_dst, 1, 16);
    aggregate<1><<<NNODES * 1, 64, 0, stream>>>(bufA, e_src, e_dst, row_ptr, col, b4,
                                                bufB, 1, 16);

    // ---- Final softmax over 16 classes ----
    softmax16<<<(NNODES + 255) / 256, 256, 0, stream>>>(bufB, (float*)d_out, NNODES);
}

// Round 2
// 638.712 us; speedup vs baseline: 2.2203x; 2.2203x over previous
//
#include <hip/hip_runtime.h>
#include <math.h>

// Problem constants (match reference setup_inputs()).
#define NNODES 10000
#define MPAD   10112           // 79 * 128 (MFMA M-tile padding)
#define NEDGES 80000           // directed edges before self loops
#define ETOT   (NEDGES + NNODES)

typedef __attribute__((ext_vector_type(4))) float f32x4;
typedef __attribute__((ext_vector_type(8))) short bf16x8;

__device__ inline unsigned short f2bf(float f) {
    unsigned int u = __float_as_uint(f);
    unsigned int r = (u + 0x7fffu + ((u >> 16) & 1u)) >> 16;
    return (unsigned short)r;
}
__device__ inline float bf2f(unsigned short h) {
    return __uint_as_float(((unsigned int)h) << 16);
}

// ---------------------------------------------------------------------------
// CSR build (group edges by destination). Rebuilt every launch (ws poisoned).
// ---------------------------------------------------------------------------
__global__ void count_deg(const int* __restrict__ ei, int* __restrict__ indeg,
                          int E, int n) {
    int i = blockIdx.x * blockDim.x + threadIdx.x;
    if (i >= E + n) return;
    int dst = (i < E) ? ei[E + i] : (i - E);
    atomicAdd(&indeg[dst], 1);
}

__global__ void scan_rowptr(const int* __restrict__ indeg, int* __restrict__ row_ptr,
                            int* __restrict__ cursor, int n) {
    __shared__ int sums[1024];
    int tid = threadIdx.x;
    int per = (n + 1023) / 1024;
    int start = tid * per;
    int end = start + per; if (end > n) end = n;
    int s = 0;
    for (int i = start; i < end; ++i) s += indeg[i];
    sums[tid] = s;
    __syncthreads();
    for (int off = 1; off < 1024; off <<= 1) {
        int v = (tid >= off) ? sums[tid - off] : 0;
        __syncthreads();
        sums[tid] += v;
        __syncthreads();
    }
    int excl = (tid == 0) ? 0 : sums[tid - 1];
    for (int i = start; i < end; ++i) {
        row_ptr[i] = excl;
        cursor[i]  = excl;
        excl += indeg[i];
    }
    if (tid == 1023) row_ptr[n] = sums[1023];
}

__global__ void scatter_edges(const int* __restrict__ ei, int* __restrict__ cursor,
                              int* __restrict__ col, int E, int n) {
    int i = blockIdx.x * blockDim.x + threadIdx.x;
    if (i >= E + n) return;
    int src, dst;
    if (i < E) { src = ei[i]; dst = ei[E + i]; }
    else       { src = i - E; dst = i - E; }
    int pos = atomicAdd(&cursor[dst], 1);
    col[pos] = src;
}

// ---------------------------------------------------------------------------
// fp32 -> bf16 elementwise convert (for x).
// ---------------------------------------------------------------------------
__global__ void convert_bf16(const float* __restrict__ in, unsigned short* __restrict__ out,
                             int n) {
    int i = blockIdx.x * blockDim.x + threadIdx.x;
    if (i < n) out[i] = f2bf(in[i]);
}

// Transpose-convert W[K][N] fp32 -> Wt[N][K] bf16. K,N multiples of 32.
__global__ void transpose_bf16(const float* __restrict__ W, unsigned short* __restrict__ Wt,
                               int K, int N) {
    __shared__ float t[32][33];
    int kb = blockIdx.y * 32, nb = blockIdx.x * 32;
    int tx = threadIdx.x, ty = threadIdx.y;   // 32 x 8
    #pragma unroll
    for (int i = 0; i < 32; i += 8)
        t[ty + i][tx] = W[(size_t)(kb + ty + i) * N + nb + tx];
    __syncthreads();
    #pragma unroll
    for (int i = 0; i < 32; i += 8)
        Wt[(size_t)(nb + ty + i) * K + kb + tx] = f2bf(t[tx][ty + i]);
}

// ---------------------------------------------------------------------------
// bf16 MFMA GEMM: C[MPAD][N] (fp32) = A[MPAD][K] (bf16) @ Bt[N][K]^T (bf16).
// Tile 128x64, 256 threads = 4 waves, each wave 64x32 via 4x2 16x16x32 MFMAs.
// K % 32 == 0, N % 64 == 0. global_load_lds width-16 staging (m97 pattern).
// ---------------------------------------------------------------------------
#define GBM 128
#define GBN 64
#define GBK 32
__global__ __launch_bounds__(256) void gemm_mfma(const unsigned short* __restrict__ A,
                                                 const unsigned short* __restrict__ Bt,
                                                 float* __restrict__ C,
                                                 int N, int K) {
    __shared__ short As[GBM * GBK];   // [128][32] row-major bf16
    __shared__ short Bs[GBN * GBK];   // [64][32]  (rows are N-dim of Bt)
    int tid  = threadIdx.x;
    int wave = tid >> 6, lane = tid & 63;
    int bm = blockIdx.y * GBM;
    int bn = blockIdx.x * GBN;
    int wr = wave >> 1, wc = wave & 1;         // wave tile origin (wr*64, wc*32)
    int lrow  = lane >> 2;                     // staging: row within 16-row chunk
    int lkoff = (lane & 3) * 8;                // staging: k offset (8 bf16 = 16B)
    int row16 = lane & 15;                     // fragment row/col within 16
    int q8    = (lane >> 4) * 8;               // fragment k offset

    f32x4 acc[4][2];
    #pragma unroll
    for (int mi = 0; mi < 4; ++mi)
        #pragma unroll
        for (int ni = 0; ni < 2; ++ni) acc[mi][ni] = (f32x4){0.f, 0.f, 0.f, 0.f};

    for (int k0 = 0; k0 < K; k0 += GBK) {
        // stage A: 8 chunks of 16 rows; wave handles chunks wave and wave+4
        #pragma unroll
        for (int i = 0; i < 2; ++i) {
            int c = i * 4 + wave;
            int row = c * 16 + lrow;
            const unsigned short* gp = A + (size_t)(bm + row) * K + k0 + lkoff;
            __builtin_amdgcn_global_load_lds(
                (const __attribute__((address_space(1))) void*)gp,
                (__attribute__((address_space(3))) void*)&As[c * 512], 16, 0, 0);
        }
        // stage Bt: 4 chunks of 16 rows; one per wave
        {
            int row = wave * 16 + lrow;
            const unsigned short* gp = Bt + (size_t)(bn + row) * K + k0 + lkoff;
            __builtin_amdgcn_global_load_lds(
                (const __attribute__((address_space(1))) void*)gp,
                (__attribute__((address_space(3))) void*)&Bs[wave * 512], 16, 0, 0);
        }
        __syncthreads();
        bf16x8 af[4], bfr[2];
        #pragma unroll
        for (int mi = 0; mi < 4; ++mi)
            af[mi] = *(const bf16x8*)&As[(wr * 64 + mi * 16 + row16) * GBK + q8];
        #pragma unroll
        for (int ni = 0; ni < 2; ++ni)
            bfr[ni] = *(const bf16x8*)&Bs[(wc * 32 + ni * 16 + row16) * GBK + q8];
        #pragma unroll
        for (int mi = 0; mi < 4; ++mi)
            #pragma unroll
            for (int ni = 0; ni < 2; ++ni)
                acc[mi][ni] = __builtin_amdgcn_mfma_f32_16x16x32_bf16(
                    af[mi], bfr[ni], acc[mi][ni], 0, 0, 0);
        __syncthreads();
    }

    // epilogue: C/D layout col = lane&15, row = (lane>>4)*4 + r
    int rbase = bm + wr * 64 + (lane >> 4) * 4;
    int cbase = bn + wc * 32 + (lane & 15);
    #pragma unroll
    for (int mi = 0; mi < 4; ++mi)
        #pragma unroll
        for (int ni = 0; ni < 2; ++ni)
            #pragma unroll
            for (int r = 0; r < 4; ++r)
                C[(size_t)(rbase + mi * 16 + r) * N + cbase + ni * 16] = acc[mi][ni][r];
}

// ---------------------------------------------------------------------------
// Tiny layer-4 GEMM: C[M][16] (fp32) = A[M][128] (bf16) @ W[128][16] (fp32).
// W staged in LDS; 16 threads per node.
// ---------------------------------------------------------------------------
__global__ __launch_bounds__(256) void gemm4(const unsigned short* __restrict__ A,
                                             const float* __restrict__ W,
                                             float* __restrict__ C, int M) {
    __shared__ float Ws[128 * 16];
    int tid = threadIdx.x;
    for (int i = tid; i < 2048; i += 256) Ws[i] = W[i];
    __syncthreads();
    int node = blockIdx.x * 16 + (tid >> 4);
    int n = tid & 15;
    if (node >= M) return;
    const unsigned short* ap = A + (size_t)node * 128;
    float acc = 0.f;
    #pragma unroll 8
    for (int k = 0; k < 128; ++k)
        acc += bf2f(ap[k]) * Ws[k * 16 + n];
    C[(size_t)node * 16 + n] = acc;
}

// ---------------------------------------------------------------------------
// e_src[n,H], e_dst[n,H]: per-(node,head) dot of h[n,h,:] with a_src/a_dst.
// ---------------------------------------------------------------------------
__global__ __launch_bounds__(64) void attn_halves(const float* __restrict__ h,
                                                  const float* __restrict__ a_src,
                                                  const float* __restrict__ a_dst,
                                                  float* __restrict__ e_src,
                                                  float* __restrict__ e_dst,
                                                  int H, int C) {
    int wid = blockIdx.x;          // node*H + head
    int head = wid % H;
    int lane = threadIdx.x;
    const float* hp = h + (size_t)wid * C;
    const float* as = a_src + head * C;
    const float* ad = a_dst + head * C;
    float s1 = 0.f, s2 = 0.f;
    for (int c = lane; c < C; c += 64) {
        float v = hp[c];
        s1 += v * as[c];
        s2 += v * ad[c];
    }
    #pragma unroll
    for (int off = 32; off; off >>= 1) {
        s1 += __shfl_down(s1, off);
        s2 += __shfl_down(s2, off);
    }
    if (lane == 0) { e_src[wid] = s1; e_dst[wid] = s2; }
}

// ---------------------------------------------------------------------------
// Aggregation: one wave per (dst,head). Segment max -> denom -> weighted sum,
// fused bias + outer LeakyReLU(0.1). Output templated: bf16 (next GEMM input)
// or fp32 (final layer).
// ---------------------------------------------------------------------------
template <int NCHUNK, typename OT>
__global__ __launch_bounds__(64) void aggregate(const float* __restrict__ h,
                                                const float* __restrict__ e_src,
                                                const float* __restrict__ e_dst,
                                                const int* __restrict__ row_ptr,
                                                const int* __restrict__ col,
                                                const float* __restrict__ bias,
                                                OT* __restrict__ out,
                                                int H, int C) {
    int wid = blockIdx.x;
    int node = wid / H;
    int head = wid - node * H;
    int lane = threadIdx.x;
    int rs = row_ptr[node], re = row_ptr[node + 1];
    float edv = e_dst[(size_t)node * H + head];

    float mx = -INFINITY;
    for (int i = rs + lane; i < re; i += 64) {
        int s = col[i];
        float v = e_src[(size_t)s * H + head] + edv;
        v = (v > 0.f) ? v : 0.2f * v;
        mx = fmaxf(mx, v);
    }
    #pragma unroll
    for (int off = 32; off; off >>= 1) mx = fmaxf(mx, __shfl_down(mx, off));
    mx = __shfl(mx, 0);

    float dn = 0.f;
    for (int i = rs + lane; i < re; i += 64) {
        int s = col[i];
        float v = e_src[(size_t)s * H + head] + edv;
        v = (v > 0.f) ? v : 0.2f * v;
        dn += expf(v - mx);
    }
    #pragma unroll
    for (int off = 32; off; off >>= 1) dn += __shfl_down(dn, off);
    dn = __shfl(dn, 0);
    float rdn = 1.f / (dn + 1e-16f);

    float acc[NCHUNK];
    #pragma unroll
    for (int k = 0; k < NCHUNK; ++k) acc[k] = 0.f;
    for (int i = rs; i < re; ++i) {
        int s = col[i];
        float v = e_src[(size_t)s * H + head] + edv;
        v = (v > 0.f) ? v : 0.2f * v;
        float w = expf(v - mx) * rdn;
        const float* hp = h + ((size_t)s * H + head) * C;
        #pragma unroll
        for (int k = 0; k < NCHUNK; ++k) {
            int c = k * 64 + lane;
            if (c < C) acc[k] += w * hp[c];
        }
    }

    OT* op = out + ((size_t)node * H + head) * C;
    const float* bp = bias + head * C;
    #pragma unroll
    for (int k = 0; k < NCHUNK; ++k) {
        int c = k * 64 + lane;
        if (c < C) {
            float v = acc[k] + bp[c];
            v = (v > 0.f) ? v : 0.1f * v;
            if constexpr (sizeof(OT) == 2) op[c] = (OT)f2bf(v);
            else                           op[c] = (OT)v;
        }
    }
}

// Final row softmax over 16 classes.
__global__ void softmax16(const float* __restrict__ in, float* __restrict__ out, int n) {
    int i = blockIdx.x * blockDim.x + threadIdx.x;
    if (i >= n) return;
    float v[16];
    float mx = -INFINITY;
    #pragma unroll
    for (int j = 0; j < 16; ++j) { v[j] = in[i * 16 + j]; mx = fmaxf(mx, v[j]); }
    float s = 0.f;
    #pragma unroll
    for (int j = 0; j < 16; ++j) { v[j] = expf(v[j] - mx); s += v[j]; }
    float r = 1.f / s;
    #pragma unroll
    for (int j = 0; j < 16; ++j) out[i * 16 + j] = v[j] * r;
}

// ---------------------------------------------------------------------------
extern "C" void kernel_launch(void* const* d_in, const int* in_sizes, int n_in,
                              void* d_out, int out_size, void* d_ws, size_t ws_size,
                              hipStream_t stream) {
    const float* x   = (const float*)d_in[0];
    const int*   ei  = (const int*)d_in[1];
    const float* W1  = (const float*)d_in[2];
    const float* as1 = (const float*)d_in[3];
    const float* ad1 = (const float*)d_in[4];
    const float* b1  = (const float*)d_in[5];
    const float* W2  = (const float*)d_in[6];
    const float* as2 = (const float*)d_in[7];
    const float* ad2 = (const float*)d_in[8];
    const float* b2  = (const float*)d_in[9];
    const float* W3  = (const float*)d_in[10];
    const float* as3 = (const float*)d_in[11];
    const float* ad3 = (const float*)d_in[12];
    const float* b3  = (const float*)d_in[13];
    const float* W4  = (const float*)d_in[14];
    const float* as4 = (const float*)d_in[15];
    const float* ad4 = (const float*)d_in[16];
    const float* b4  = (const float*)d_in[17];

    char* ws = (char*)d_ws;
    size_t off = 0;
    auto alloc = [&](size_t bytes) -> void* {
        void* p = ws + off;
        off = (off + bytes + 255) & ~(size_t)255;
        return p;
    };
    float*          hbuf = (float*)alloc((size_t)MPAD * 2560 * sizeof(float));          // GEMM C / attn input
    unsigned short* abuf = (unsigned short*)alloc((size_t)MPAD * 2560 * sizeof(short)); // bf16 GEMM A input
    unsigned short* W1t  = (unsigned short*)alloc((size_t)2560 * 128 * sizeof(short));
    unsigned short* W2t  = (unsigned short*)alloc((size_t)448 * 2560 * sizeof(short));
    unsigned short* W3t  = (unsigned short*)alloc((size_t)128 * 448 * sizeof(short));
    float* out4   = (float*)alloc((size_t)NNODES * 16 * sizeof(float));
    float* e_src  = (float*)alloc((size_t)NNODES * 10 * sizeof(float));
    float* e_dst  = (float*)alloc((size_t)NNODES * 10 * sizeof(float));
    int* indeg    = (int*)alloc(NNODES * sizeof(int));
    int* row_ptr  = (int*)alloc((NNODES + 1) * sizeof(int));
    int* cursor   = (int*)alloc(NNODES * sizeof(int));
    int* col      = (int*)alloc(ETOT * sizeof(int));
    (void)ws_size;

    // ---- CSR build ----
    hipMemsetAsync(indeg, 0, NNODES * sizeof(int), stream);
    int eb = (ETOT + 255) / 256;
    count_deg<<<eb, 256, 0, stream>>>(ei, indeg, NEDGES, NNODES);
    scan_rowptr<<<1, 1024, 0, stream>>>(indeg, row_ptr, cursor, NNODES);
    scatter_edges<<<eb, 256, 0, stream>>>(ei, cursor, col, NEDGES, NNODES);

    // ---- weight transposes + x convert ----
    transpose_bf16<<<dim3(2560 / 32, 128 / 32), dim3(32, 8), 0, stream>>>(W1, W1t, 128, 2560);
    transpose_bf16<<<dim3(448 / 32, 2560 / 32), dim3(32, 8), 0, stream>>>(W2, W2t, 2560, 448);
    transpose_bf16<<<dim3(128 / 32, 448 / 32), dim3(32, 8), 0, stream>>>(W3, W3t, 448, 128);
    convert_bf16<<<(NNODES * 128 + 255) / 256, 256, 0, stream>>>(x, abuf, NNODES * 128);

    const int Mb = MPAD / GBM;   // 79

    // ---- Layer 1: 128 -> 10 heads x 256, concat ----
    gemm_mfma<<<dim3(2560 / GBN, Mb), 256, 0, stream>>>(abuf, W1t, hbuf, 2560, 128);
    attn_halves<<<NNODES * 10, 64, 0, stream>>>(hbuf, as1, ad1, e_src, e_dst, 10, 256);
    aggregate<4, unsigned short><<<NNODES * 10, 64, 0, stream>>>(
        hbuf, e_src, e_dst, row_ptr, col, b1, abuf, 10, 256);

    // ---- Layer 2: 2560 -> 8 heads x 56, concat ----
    gemm_mfma<<<dim3(448 / GBN, Mb), 256, 0, stream>>>(abuf, W2t, hbuf, 448, 2560);
    attn_halves<<<NNODES * 8, 64, 0, stream>>>(hbuf, as2, ad2, e_src, e_dst, 8, 56);
    aggregate<1, unsigned short><<<NNODES * 8, 64, 0, stream>>>(
        hbuf, e_src, e_dst, row_ptr, col, b2, abuf, 8, 56);

    // ---- Layer 3: 448 -> 4 heads x 32, concat ----
    gemm_mfma<<<dim3(128 / GBN, Mb), 256, 0, stream>>>(abuf, W3t, hbuf, 128, 448);
    attn_halves<<<NNODES * 4, 64, 0, stream>>>(hbuf, as3, ad3, e_src, e_dst, 4, 32);
    aggregate<1, unsigned short><<<NNODES * 4, 64, 0, stream>>>(
        hbuf, e_src, e_dst, row_ptr, col, b3, abuf, 4, 32);

    // ---- Layer 4: 128 -> 1 head x 16, mean(=identity) ----
    gemm4<<<(NNODES + 15) / 16, 256, 0, stream>>>(abuf, W4, hbuf, NNODES);
    attn_halves<<<NNODES, 64, 0, stream>>>(hbuf, as4, ad4, e_src, e_dst, 1, 16);
    aggregate<1, float><<<NNODES, 64, 0, stream>>>(
        hbuf, e_src, e_dst, row_ptr, col, b4, out4, 1, 16);

    // ---- Final softmax over 16 classes ----
    softmax16<<<(NNODES + 255) / 256, 256, 0, stream>>>(out4, (float*)d_out, NNODES);
}

// Round 3
// 457.185 us; speedup vs baseline: 3.1019x; 1.3971x over previous
//
#include <hip/hip_runtime.h>
#include <math.h>

// Problem constants (match reference setup_inputs()).
#define NNODES 10000
#define MPAD   10112           // 79 * 128 (MFMA M-tile padding)
#define NEDGES 80000           // directed edges before self loops
#define ETOT   (NEDGES + NNODES)

typedef __attribute__((ext_vector_type(4))) float f32x4;
typedef __attribute__((ext_vector_type(8))) short bf16x8;
typedef __attribute__((ext_vector_type(4))) unsigned short u16x4;

__device__ inline unsigned short f2bf(float f) {
    unsigned int u = __float_as_uint(f);
    unsigned int r = (u + 0x7fffu + ((u >> 16) & 1u)) >> 16;
    return (unsigned short)r;
}
__device__ inline float bf2f(unsigned short h) {
    return __uint_as_float(((unsigned int)h) << 16);
}

// ---------------------------------------------------------------------------
// CSR build (group edges by destination). Rebuilt every launch (ws poisoned).
// ---------------------------------------------------------------------------
__global__ void count_deg(const int* __restrict__ ei, int* __restrict__ indeg,
                          int E, int n) {
    int i = blockIdx.x * blockDim.x + threadIdx.x;
    if (i >= E + n) return;
    int dst = (i < E) ? ei[E + i] : (i - E);
    atomicAdd(&indeg[dst], 1);
}

__global__ void scan_rowptr(const int* __restrict__ indeg, int* __restrict__ row_ptr,
                            int* __restrict__ cursor, int n) {
    __shared__ int sums[1024];
    int tid = threadIdx.x;
    int per = (n + 1023) / 1024;
    int start = tid * per;
    int end = start + per; if (end > n) end = n;
    int s = 0;
    for (int i = start; i < end; ++i) s += indeg[i];
    sums[tid] = s;
    __syncthreads();
    for (int off = 1; off < 1024; off <<= 1) {
        int v = (tid >= off) ? sums[tid - off] : 0;
        __syncthreads();
        sums[tid] += v;
        __syncthreads();
    }
    int excl = (tid == 0) ? 0 : sums[tid - 1];
    for (int i = start; i < end; ++i) {
        row_ptr[i] = excl;
        cursor[i]  = excl;
        excl += indeg[i];
    }
    if (tid == 1023) row_ptr[n] = sums[1023];
}

__global__ void scatter_edges(const int* __restrict__ ei, int* __restrict__ cursor,
                              int* __restrict__ col, int E, int n) {
    int i = blockIdx.x * blockDim.x + threadIdx.x;
    if (i >= E + n) return;
    int src, dst;
    if (i < E) { src = ei[i]; dst = ei[E + i]; }
    else       { src = i - E; dst = i - E; }
    int pos = atomicAdd(&cursor[dst], 1);
    col[pos] = src;
}

// ---------------------------------------------------------------------------
// fp32 -> bf16 elementwise convert (for x).
// ---------------------------------------------------------------------------
__global__ void convert_bf16(const float* __restrict__ in, unsigned short* __restrict__ out,
                             int n) {
    int i = blockIdx.x * blockDim.x + threadIdx.x;
    if (i < n) out[i] = f2bf(in[i]);
}

// Transpose-convert W[K][N] fp32 -> Wt[N][K] bf16. K,N multiples of 32.
__global__ void transpose_bf16(const float* __restrict__ W, unsigned short* __restrict__ Wt,
                               int K, int N) {
    __shared__ float t[32][33];
    int kb = blockIdx.y * 32, nb = blockIdx.x * 32;
    int tx = threadIdx.x, ty = threadIdx.y;   // 32 x 8
    #pragma unroll
    for (int i = 0; i < 32; i += 8)
        t[ty + i][tx] = W[(size_t)(kb + ty + i) * N + nb + tx];
    __syncthreads();
    #pragma unroll
    for (int i = 0; i < 32; i += 8)
        Wt[(size_t)(nb + ty + i) * K + kb + tx] = f2bf(t[tx][ty + i]);
}

// ---------------------------------------------------------------------------
// bf16 MFMA GEMM: C[MPAD][N] (bf16 out) = A[MPAD][K] (bf16) @ Bt[N][K]^T.
// Tile 128x64, 256 threads = 4 waves, each wave 64x32 via 4x2 16x16x32 MFMAs.
// ---------------------------------------------------------------------------
#define GBM 128
#define GBN 64
#define GBK 32
__global__ __launch_bounds__(256) void gemm_mfma(const unsigned short* __restrict__ A,
                                                 const unsigned short* __restrict__ Bt,
                                                 unsigned short* __restrict__ C,
                                                 int N, int K) {
    __shared__ short As[GBM * GBK];
    __shared__ short Bs[GBN * GBK];
    int tid  = threadIdx.x;
    int wave = tid >> 6, lane = tid & 63;
    int bm = blockIdx.y * GBM;
    int bn = blockIdx.x * GBN;
    int wr = wave >> 1, wc = wave & 1;
    int lrow  = lane >> 2;
    int lkoff = (lane & 3) * 8;
    int row16 = lane & 15;
    int q8    = (lane >> 4) * 8;

    f32x4 acc[4][2];
    #pragma unroll
    for (int mi = 0; mi < 4; ++mi)
        #pragma unroll
        for (int ni = 0; ni < 2; ++ni) acc[mi][ni] = (f32x4){0.f, 0.f, 0.f, 0.f};

    for (int k0 = 0; k0 < K; k0 += GBK) {
        #pragma unroll
        for (int i = 0; i < 2; ++i) {
            int c = i * 4 + wave;
            int row = c * 16 + lrow;
            const unsigned short* gp = A + (size_t)(bm + row) * K + k0 + lkoff;
            __builtin_amdgcn_global_load_lds(
                (const __attribute__((address_space(1))) void*)gp,
                (__attribute__((address_space(3))) void*)&As[c * 512], 16, 0, 0);
        }
        {
            int row = wave * 16 + lrow;
            const unsigned short* gp = Bt + (size_t)(bn + row) * K + k0 + lkoff;
            __builtin_amdgcn_global_load_lds(
                (const __attribute__((address_space(1))) void*)gp,
                (__attribute__((address_space(3))) void*)&Bs[wave * 512], 16, 0, 0);
        }
        __syncthreads();
        bf16x8 af[4], bfr[2];
        #pragma unroll
        for (int mi = 0; mi < 4; ++mi)
            af[mi] = *(const bf16x8*)&As[(wr * 64 + mi * 16 + row16) * GBK + q8];
        #pragma unroll
        for (int ni = 0; ni < 2; ++ni)
            bfr[ni] = *(const bf16x8*)&Bs[(wc * 32 + ni * 16 + row16) * GBK + q8];
        #pragma unroll
        for (int mi = 0; mi < 4; ++mi)
            #pragma unroll
            for (int ni = 0; ni < 2; ++ni)
                acc[mi][ni] = __builtin_amdgcn_mfma_f32_16x16x32_bf16(
                    af[mi], bfr[ni], acc[mi][ni], 0, 0, 0);
        __syncthreads();
    }

    int rbase = bm + wr * 64 + (lane >> 4) * 4;
    int cbase = bn + wc * 32 + (lane & 15);
    #pragma unroll
    for (int mi = 0; mi < 4; ++mi)
        #pragma unroll
        for (int ni = 0; ni < 2; ++ni)
            #pragma unroll
            for (int r = 0; r < 4; ++r)
                C[(size_t)(rbase + mi * 16 + r) * N + cbase + ni * 16] =
                    f2bf(acc[mi][ni][r]);
}

// ---------------------------------------------------------------------------
// Tiny layer-4 GEMM: C[M][16] (bf16) = A[M][128] (bf16) @ W[128][16] (fp32).
// ---------------------------------------------------------------------------
__global__ __launch_bounds__(256) void gemm4(const unsigned short* __restrict__ A,
                                             const float* __restrict__ W,
                                             unsigned short* __restrict__ C, int M) {
    __shared__ float Ws[128 * 16];
    int tid = threadIdx.x;
    for (int i = tid; i < 2048; i += 256) Ws[i] = W[i];
    __syncthreads();
    int node = blockIdx.x * 16 + (tid >> 4);
    int n = tid & 15;
    if (node >= M) return;
    const unsigned short* ap = A + (size_t)node * 128;
    float acc = 0.f;
    #pragma unroll 8
    for (int k = 0; k < 128; ++k)
        acc += bf2f(ap[k]) * Ws[k * 16 + n];
    C[(size_t)node * 16 + n] = f2bf(acc);
}

// ---------------------------------------------------------------------------
// e_src[n,H], e_dst[n,H]: per-(node,head) dot of bf16 h[n,h,:] with a_src/a_dst.
// ---------------------------------------------------------------------------
__global__ __launch_bounds__(64) void attn_halves(const unsigned short* __restrict__ h,
                                                  const float* __restrict__ a_src,
                                                  const float* __restrict__ a_dst,
                                                  float* __restrict__ e_src,
                                                  float* __restrict__ e_dst,
                                                  int H, int C) {
    int wid = blockIdx.x;          // node*H + head
    int head = wid % H;
    int lane = threadIdx.x;
    const unsigned short* hp = h + (size_t)wid * C;
    float s1 = 0.f, s2 = 0.f;
    for (int c0 = lane * 4; c0 < C; c0 += 256) {
        u16x4 hv = *(const u16x4*)&hp[c0];
        f32x4 as = *(const f32x4*)&a_src[head * C + c0];
        f32x4 ad = *(const f32x4*)&a_dst[head * C + c0];
        #pragma unroll
        for (int j = 0; j < 4; ++j) {
            float v = bf2f(hv[j]);
            s1 += v * as[j];
            s2 += v * ad[j];
        }
    }
    #pragma unroll
    for (int off = 32; off; off >>= 1) {
        s1 += __shfl_down(s1, off);
        s2 += __shfl_down(s2, off);
    }
    if (lane == 0) { e_src[wid] = s1; e_dst[wid] = s2; }
}

// ---------------------------------------------------------------------------
// Aggregation, wide (C=256, layer 1): wave = (node,head,chunk), 128 ch/wave
// via packed bf16x2 gathers. Two passes: max, then fused exp-sum + weighted
// accumulate; normalize by denom at the end. Fused bias + LeakyReLU(0.1).
// ---------------------------------------------------------------------------
__global__ __launch_bounds__(64) void aggregate_wide(const unsigned int* __restrict__ h2,
                                                     const float* __restrict__ e_src,
                                                     const float* __restrict__ e_dst,
                                                     const int* __restrict__ row_ptr,
                                                     const int* __restrict__ col,
                                                     const float* __restrict__ bias,
                                                     unsigned int* __restrict__ out2,
                                                     int H) {
    const int C = 256;
    int wid = blockIdx.x;
    int chunk = wid & 1;
    int nh = wid >> 1;                 // node*H + head
    int node = nh / H;
    int head = nh - node * H;
    int lane = threadIdx.x;
    int rs = row_ptr[node], re = row_ptr[node + 1];
    float edv = e_dst[nh];

    // pass A: segment max
    float mx = -INFINITY;
    for (int i = rs + lane; i < re; i += 64) {
        int s = col[i];
        float v = e_src[s * H + head] + edv;
        v = (v > 0.f) ? v : 0.2f * v;
        mx = fmaxf(mx, v);
    }
    #pragma unroll
    for (int off = 32; off; off >>= 1) mx = fmaxf(mx, __shfl_down(mx, off));
    mx = __shfl(mx, 0);

    // pass B: fused denom + weighted gather-accumulate (bf16x2)
    float dn = 0.f, acc0 = 0.f, acc1 = 0.f;
    #pragma unroll 2
    for (int i = rs; i < re; ++i) {
        int s = col[i];
        float v = e_src[s * H + head] + edv;
        v = (v > 0.f) ? v : 0.2f * v;
        float w = __expf(v - mx);
        dn += w;
        unsigned int hv = h2[(size_t)(s * H + head) * (C / 2) + chunk * 64 + lane];
        acc0 += w * bf2f((unsigned short)(hv & 0xffffu));
        acc1 += w * bf2f((unsigned short)(hv >> 16));
    }
    float rdn = 1.f / (dn + 1e-16f);

    int c0 = chunk * 128 + lane * 2;
    float v0 = acc0 * rdn + bias[head * C + c0];
    float v1 = acc1 * rdn + bias[head * C + c0 + 1];
    v0 = (v0 > 0.f) ? v0 : 0.1f * v0;
    v1 = (v1 > 0.f) ? v1 : 0.1f * v1;
    out2[(size_t)nh * (C / 2) + chunk * 64 + lane] =
        (unsigned int)f2bf(v0) | ((unsigned int)f2bf(v1) << 16);
}

// ---------------------------------------------------------------------------
// Aggregation, small C (<=64 channels per head). HPW = heads per wave (1 or 2).
// For HPW=2 the two head slices are contiguous (head*C + ch == hp*2C + lane).
// ---------------------------------------------------------------------------
template <int C, int HPW, typename OT>
__global__ __launch_bounds__(64) void aggregate_small(const unsigned short* __restrict__ h,
                                                      const float* __restrict__ e_src,
                                                      const float* __restrict__ e_dst,
                                                      const int* __restrict__ row_ptr,
                                                      const int* __restrict__ col,
                                                      const float* __restrict__ bias,
                                                      OT* __restrict__ out,
                                                      int H) {
    constexpr int STRIDE = 64 / HPW;       // edge-stride per sub-wave
    int wid = blockIdx.x;                  // node * (H/HPW) + headgroup
    int ngroups = H / HPW;
    int node = wid / ngroups;
    int hg   = wid - node * ngroups;
    int lane = threadIdx.x;
    int sub  = (HPW == 2) ? (lane >> 5) : 0;
    int head = hg * HPW + sub;
    int ch   = (HPW == 2) ? (lane & 31) : lane;
    int rs = row_ptr[node], re = row_ptr[node + 1];
    float edv = e_dst[node * H + head];

    // pass A: per-head segment max (each sub-wave strides independently)
    float mx = -INFINITY;
    for (int i = rs + ch; i < re; i += STRIDE) {
        int s = col[i];
        float v = e_src[s * H + head] + edv;
        v = (v > 0.f) ? v : 0.2f * v;
        mx = fmaxf(mx, v);
    }
    #pragma unroll
    for (int off = STRIDE / 2; off; off >>= 1) mx = fmaxf(mx, __shfl_down(mx, off));
    mx = __shfl(mx, lane & ~(STRIDE - 1));

    // pass B: fused denom + weighted gather
    float dn = 0.f, acc = 0.f;
    #pragma unroll 2
    for (int i = rs; i < re; ++i) {
        int s = col[i];
        float v = e_src[s * H + head] + edv;
        v = (v > 0.f) ? v : 0.2f * v;
        float w = __expf(v - mx);
        dn += w;
        unsigned short hv = h[(size_t)(s * H + head) * C + ch];
        acc += w * bf2f(hv);
    }
    float rdn = 1.f / (dn + 1e-16f);

    if (ch < C) {
        float v = acc * rdn + bias[head * C + ch];
        v = (v > 0.f) ? v : 0.1f * v;
        OT* op = out + (size_t)(node * H + head) * C + ch;
        if constexpr (sizeof(OT) == 2) *op = (OT)f2bf(v);
        else                           *op = (OT)v;
    }
}

// Final row softmax over 16 classes.
__global__ void softmax16(const float* __restrict__ in, float* __restrict__ out, int n) {
    int i = blockIdx.x * blockDim.x + threadIdx.x;
    if (i >= n) return;
    float v[16];
    float mx = -INFINITY;
    #pragma unroll
    for (int j = 0; j < 16; ++j) { v[j] = in[i * 16 + j]; mx = fmaxf(mx, v[j]); }
    float s = 0.f;
    #pragma unroll
    for (int j = 0; j < 16; ++j) { v[j] = expf(v[j] - mx); s += v[j]; }
    float r = 1.f / s;
    #pragma unroll
    for (int j = 0; j < 16; ++j) out[i * 16 + j] = v[j] * r;
}

// ---------------------------------------------------------------------------
extern "C" void kernel_launch(void* const* d_in, const int* in_sizes, int n_in,
                              void* d_out, int out_size, void* d_ws, size_t ws_size,
                              hipStream_t stream) {
    const float* x   = (const float*)d_in[0];
    const int*   ei  = (const int*)d_in[1];
    const float* W1  = (const float*)d_in[2];
    const float* as1 = (const float*)d_in[3];
    const float* ad1 = (const float*)d_in[4];
    const float* b1  = (const float*)d_in[5];
    const float* W2  = (const float*)d_in[6];
    const float* as2 = (const float*)d_in[7];
    const float* ad2 = (const float*)d_in[8];
    const float* b2  = (const float*)d_in[9];
    const float* W3  = (const float*)d_in[10];
    const float* as3 = (const float*)d_in[11];
    const float* ad3 = (const float*)d_in[12];
    const float* b3  = (const float*)d_in[13];
    const float* W4  = (const float*)d_in[14];
    const float* as4 = (const float*)d_in[15];
    const float* ad4 = (const float*)d_in[16];
    const float* b4  = (const float*)d_in[17];

    char* ws = (char*)d_ws;
    size_t off = 0;
    auto alloc = [&](size_t bytes) -> void* {
        void* p = ws + off;
        off = (off + bytes + 255) & ~(size_t)255;
        return p;
    };
    unsigned short* hbuf = (unsigned short*)alloc((size_t)MPAD * 2560 * sizeof(short)); // GEMM out / attn input
    unsigned short* abuf = (unsigned short*)alloc((size_t)MPAD * 2560 * sizeof(short)); // bf16 GEMM A input
    unsigned short* W1t  = (unsigned short*)alloc((size_t)2560 * 128 * sizeof(short));
    unsigned short* W2t  = (unsigned short*)alloc((size_t)448 * 2560 * sizeof(short));
    unsigned short* W3t  = (unsigned short*)alloc((size_t)128 * 448 * sizeof(short));
    float* out4   = (float*)alloc((size_t)NNODES * 16 * sizeof(float));
    float* e_src  = (float*)alloc((size_t)NNODES * 10 * sizeof(float));
    float* e_dst  = (float*)alloc((size_t)NNODES * 10 * sizeof(float));
    int* indeg    = (int*)alloc(NNODES * sizeof(int));
    int* row_ptr  = (int*)alloc((NNODES + 1) * sizeof(int));
    int* cursor   = (int*)alloc(NNODES * sizeof(int));
    int* col      = (int*)alloc(ETOT * sizeof(int));
    (void)ws_size;

    // ---- CSR build ----
    hipMemsetAsync(indeg, 0, NNODES * sizeof(int), stream);
    int eb = (ETOT + 255) / 256;
    count_deg<<<eb, 256, 0, stream>>>(ei, indeg, NEDGES, NNODES);
    scan_rowptr<<<1, 1024, 0, stream>>>(indeg, row_ptr, cursor, NNODES);
    scatter_edges<<<eb, 256, 0, stream>>>(ei, cursor, col, NEDGES, NNODES);

    // ---- weight transposes + x convert ----
    transpose_bf16<<<dim3(2560 / 32, 128 / 32), dim3(32, 8), 0, stream>>>(W1, W1t, 128, 2560);
    transpose_bf16<<<dim3(448 / 32, 2560 / 32), dim3(32, 8), 0, stream>>>(W2, W2t, 2560, 448);
    transpose_bf16<<<dim3(128 / 32, 448 / 32), dim3(32, 8), 0, stream>>>(W3, W3t, 448, 128);
    convert_bf16<<<(NNODES * 128 + 255) / 256, 256, 0, stream>>>(x, abuf, NNODES * 128);

    const int Mb = MPAD / GBM;   // 79

    // ---- Layer 1: 128 -> 10 heads x 256, concat ----
    gemm_mfma<<<dim3(2560 / GBN, Mb), 256, 0, stream>>>(abuf, W1t, hbuf, 2560, 128);
    attn_halves<<<NNODES * 10, 64, 0, stream>>>(hbuf, as1, ad1, e_src, e_dst, 10, 256);
    aggregate_wide<<<NNODES * 10 * 2, 64, 0, stream>>>(
        (const unsigned int*)hbuf, e_src, e_dst, row_ptr, col, b1,
        (unsigned int*)abuf, 10);

    // ---- Layer 2: 2560 -> 8 heads x 56, concat ----
    gemm_mfma<<<dim3(448 / GBN, Mb), 256, 0, stream>>>(abuf, W2t, hbuf, 448, 2560);
    attn_halves<<<NNODES * 8, 64, 0, stream>>>(hbuf, as2, ad2, e_src, e_dst, 8, 56);
    aggregate_small<56, 1, unsigned short><<<NNODES * 8, 64, 0, stream>>>(
        hbuf, e_src, e_dst, row_ptr, col, b2, abuf, 8);

    // ---- Layer 3: 448 -> 4 heads x 32, concat ----
    gemm_mfma<<<dim3(128 / GBN, Mb), 256, 0, stream>>>(abuf, W3t, hbuf, 128, 448);
    attn_halves<<<NNODES * 4, 64, 0, stream>>>(hbuf, as3, ad3, e_src, e_dst, 4, 32);
    aggregate_small<32, 2, unsigned short><<<NNODES * 2, 64, 0, stream>>>(
        hbuf, e_src, e_dst, row_ptr, col, b3, abuf, 4);

    // ---- Layer 4: 128 -> 1 head x 16, mean(=identity) ----
    gemm4<<<(NNODES + 15) / 16, 256, 0, stream>>>(abuf, W4, hbuf, NNODES);
    attn_halves<<<NNODES, 64, 0, stream>>>(hbuf, as4, ad4, e_src, e_dst, 1, 16);
    aggregate_small<16, 1, float><<<NNODES, 64, 0, stream>>>(
        hbuf, e_src, e_dst, row_ptr, col, b4, out4, 1);

    // ---- Final softmax over 16 classes ----
    softmax16<<<(NNODES + 255) / 256, 256, 0, stream>>>(out4, (float*)d_out, NNODES);
}